// Round 3
// baseline (820.248 us; speedup 1.0000x reference)
//
#include <hip/hip_runtime.h>
#include <hip/hip_bf16.h>

#define NN 50000
#define NE 800000
#define NG 512

typedef __bf16 bf16_t;
typedef __bf16 bf16x8 __attribute__((ext_vector_type(8)));
typedef float f32x4 __attribute__((ext_vector_type(4)));

// PARAMS f32 scratch layout (element offsets)
#define O_EMB    0        // 51*128
#define O_C1L2W  6528     // 128*4
#define O_C1L2B  7040     // 128
#define O_C1LW   7168     // 256*128
#define O_C1LB   39936    // 256
#define O_BN1W   40192    // 256
#define O_BN1B   40448    // 256
#define O_C2L2W  40704    // 256*4
#define O_C2L2B  41728    // 256
#define O_C2LW   41984    // 256*256
#define O_C2LB   107520   // 256
#define O_BN2W   107776   // 256
#define O_BN2B   108032   // 256
#define O_GATEW  108288   // 256
#define O_GATEB  108544   // 1
#define NPAR     108545

__device__ __forceinline__ float lrelu(float v) { return v >= 0.f ? v : 0.01f * v; }
__device__ __forceinline__ float b2f(unsigned short u) {
    union { unsigned v; float f; } x; x.v = ((unsigned)u) << 16; return x.f;
}

// ---------------- dtype probe: bn1_w is all-ones ----------------
// f32 word0 = 0x3F800000 ; bf16-pair word0 = 0x3F803F80
__global__ void gme_mode(const unsigned* __restrict__ bn1w_raw, int* __restrict__ MODE) {
    if (threadIdx.x == 0) MODE[0] = (bn1w_raw[0] == 0x3F800000u) ? 0 : 1;
}

// ---------------- widen all float params to f32 scratch ----------------
__global__ void gme_cvt(const void* s0, const void* s1, const void* s2, const void* s3,
                        const void* s4, const void* s5, const void* s6, const void* s7,
                        const void* s8, const void* s9, const void* s10, const void* s11,
                        const void* s12, const void* s13, const void* s14,
                        const int* __restrict__ MODE, float* __restrict__ PR) {
    int i = blockIdx.x * 256 + threadIdx.x;
    if (i >= NPAR) return;
    int mode = MODE[0];
    const void* src; int off;
    if      (i < O_C1L2W) { src = s0;  off = i; }
    else if (i < O_C1L2B) { src = s1;  off = i - O_C1L2W; }
    else if (i < O_C1LW)  { src = s2;  off = i - O_C1L2B; }
    else if (i < O_C1LB)  { src = s3;  off = i - O_C1LW; }
    else if (i < O_BN1W)  { src = s4;  off = i - O_C1LB; }
    else if (i < O_BN1B)  { src = s5;  off = i - O_BN1W; }
    else if (i < O_C2L2W) { src = s6;  off = i - O_BN1B; }
    else if (i < O_C2L2B) { src = s7;  off = i - O_C2L2W; }
    else if (i < O_C2LW)  { src = s8;  off = i - O_C2L2B; }
    else if (i < O_C2LB)  { src = s9;  off = i - O_C2LW; }
    else if (i < O_BN2W)  { src = s10; off = i - O_C2LB; }
    else if (i < O_BN2B)  { src = s11; off = i - O_BN2W; }
    else if (i < O_GATEW) { src = s12; off = i - O_BN2B; }
    else if (i < O_GATEB) { src = s13; off = i - O_GATEW; }
    else                  { src = s14; off = i - O_GATEB; }
    float v = mode ? b2f(((const unsigned short*)src)[off]) : ((const float*)src)[off];
    PR[i] = v;
}

// ---------------- tiny precomputes ----------------
// grid 117 x 256:
//  b<51: TY[b][t]=dot(emb[b],W1[t]);  b==51: WC1/CB1;  b==52: WC2/CB2;  b>=53: W2 bf16
__global__ void gme_setup(const float* __restrict__ PR,
                          float* __restrict__ TY, float* __restrict__ WC1, float* __restrict__ CB1,
                          float* __restrict__ WC2, float* __restrict__ CB2,
                          bf16_t* __restrict__ W2B) {
    int b = blockIdx.x, t = threadIdx.x;
    if (b < 51) {
        const float* er = PR + O_EMB + b * 128;
        const float* wr = PR + O_C1LW + t * 128;
        float s = 0.f;
        for (int k = 0; k < 128; ++k) s += er[k] * wr[k];
        TY[b * 256 + t] = s;
    } else if (b == 51) {
        const float* wr = PR + O_C1LW + t * 128;
        const float* l2w = PR + O_C1L2W;
        const float* l2b = PR + O_C1L2B;
        float a0 = 0, a1 = 0, a2 = 0, a3 = 0, ab = 0;
        for (int k = 0; k < 128; ++k) {
            float w = wr[k];
            a0 += w * l2w[k * 4 + 0]; a1 += w * l2w[k * 4 + 1];
            a2 += w * l2w[k * 4 + 2]; a3 += w * l2w[k * 4 + 3];
            ab += w * l2b[k];
        }
        WC1[t * 4 + 0] = a0; WC1[t * 4 + 1] = a1; WC1[t * 4 + 2] = a2; WC1[t * 4 + 3] = a3;
        CB1[t] = ab + PR[O_C1LB + t];
    } else if (b == 52) {
        const float* wr = PR + O_C2LW + t * 256;
        const float* l2w = PR + O_C2L2W;
        const float* l2b = PR + O_C2L2B;
        float a0 = 0, a1 = 0, a2 = 0, a3 = 0, ab = 0;
        for (int k = 0; k < 256; ++k) {
            float w = wr[k];
            a0 += w * l2w[k * 4 + 0]; a1 += w * l2w[k * 4 + 1];
            a2 += w * l2w[k * 4 + 2]; a3 += w * l2w[k * 4 + 3];
            ab += w * l2b[k];
        }
        WC2[t * 4 + 0] = a0; WC2[t * 4 + 1] = a1; WC2[t * 4 + 2] = a2; WC2[t * 4 + 3] = a3;
        CB2[t] = ab + PR[O_C2LB + t];
    } else {
        int i0 = (b - 53) * 1024;
        for (int r = 0; r < 4; ++r) {
            int i = i0 + r * 256 + t;
            W2B[i] = (bf16_t)PR[O_C2LW + i];
        }
    }
}

// ---------------- CSR build ----------------
__global__ void gme_count(const int* __restrict__ ei, int* __restrict__ cnt) {
    int e = blockIdx.x * 256 + threadIdx.x;
    if (e >= NE) return;
    atomicAdd(&cnt[ei[NE + e]], 1);
}

__global__ void gme_scan(int* __restrict__ CUR, int* __restrict__ RS) {
    __shared__ int lds[1024];
    int t = threadIdx.x;
    int base = t * 49;
    int end = base + 49; if (end > NN) end = NN;
    int s = 0;
    for (int i = base; i < end; ++i) s += CUR[i];
    lds[t] = s;
    __syncthreads();
    for (int off = 1; off < 1024; off <<= 1) {
        int v = (t >= off) ? lds[t - off] : 0;
        __syncthreads();
        lds[t] += v;
        __syncthreads();
    }
    int run = lds[t] - s;  // exclusive prefix
    for (int i = base; i < end; ++i) {
        int c = CUR[i];
        RS[i] = run;
        CUR[i] = run;  // cursor init for scatter
        run += c;
    }
    if (t == 1023) RS[NN] = lds[1023];
}

__global__ void gme_scatter(const int* __restrict__ ei, const void* __restrict__ eattr_raw,
                            const int* __restrict__ MODE,
                            int* __restrict__ CUR, int* __restrict__ Ssrc,
                            float4* __restrict__ Sattr) {
    int e = blockIdx.x * 256 + threadIdx.x;
    if (e >= NE) return;
    int mode = MODE[0];
    int d = ei[NE + e];
    int pos = atomicAdd(&CUR[d], 1);
    Ssrc[pos] = ei[e];
    float4 a;
    if (mode) {
        const unsigned short* p = (const unsigned short*)eattr_raw + e * 4;
        a = make_float4(b2f(p[0]), b2f(p[1]), b2f(p[2]), b2f(p[3]));
    } else {
        a = ((const float4*)eattr_raw)[e];
    }
    Sattr[pos] = a;
}

// ---------------- edge aggregation (both convs) ----------------
// one wave per destination node; lane handles 4 channels
__global__ __launch_bounds__(256) void gme_conv(
        const int* __restrict__ RS, const int* __restrict__ Ssrc,
        const float4* __restrict__ Sattr, const float* __restrict__ ybase,
        const int* __restrict__ remap, const float* __restrict__ Wc,
        const float* __restrict__ cb, float* __restrict__ agg) {
    int lane = threadIdx.x & 63;
    int node = blockIdx.x * 4 + (threadIdx.x >> 6);
    if (node >= NN) return;
    const float4* wc4 = (const float4*)Wc;
    int c4 = lane * 4;
    float4 w0 = wc4[c4 + 0], w1 = wc4[c4 + 1], w2 = wc4[c4 + 2], w3 = wc4[c4 + 3];
    float4 bz = ((const float4*)cb)[lane];
    float ax = 0.f, ay = 0.f, az = 0.f, aw = 0.f;
    int rs = RS[node], re = RS[node + 1];
    for (int j = rs; j < re; ++j) {
        int s = Ssrc[j];
        int row = remap ? remap[s] : s;
        float4 a = Sattr[j];
        float4 y = *((const float4*)(ybase + row * 256) + lane);
        float m0 = fmaf(a.x, w0.x, fmaf(a.y, w0.y, fmaf(a.z, w0.z, fmaf(a.w, w0.w, bz.x)))) + y.x;
        float m1 = fmaf(a.x, w1.x, fmaf(a.y, w1.y, fmaf(a.z, w1.z, fmaf(a.w, w1.w, bz.y)))) + y.y;
        float m2 = fmaf(a.x, w2.x, fmaf(a.y, w2.y, fmaf(a.z, w2.z, fmaf(a.w, w2.w, bz.z)))) + y.z;
        float m3 = fmaf(a.x, w3.x, fmaf(a.y, w3.y, fmaf(a.z, w3.z, fmaf(a.w, w3.w, bz.w)))) + y.w;
        ax += lrelu(m0); ay += lrelu(m1); az += lrelu(m2); aw += lrelu(m3);
    }
    float4 acc = make_float4(ax, ay, az, aw);
    *((float4*)(agg + node * 256) + lane) = acc;
}

// ---------------- BN stats ----------------
__global__ void gme_bnstats(const float* __restrict__ P, float* __restrict__ ST) {
    int c = threadIdx.x;
    float s = 0.f, q = 0.f;
    for (int n = blockIdx.x; n < NN; n += gridDim.x) {
        float v = P[n * 256 + c];
        s += v; q += v * v;
    }
    atomicAdd(&ST[c], s);
    atomicAdd(&ST[256 + c], q);
}

// ---------------- BN1 + LeakyReLU -> bf16 ----------------
__global__ void gme_x1bf16(const float* __restrict__ P, const float* __restrict__ ST,
                           const float* __restrict__ PR, bf16_t* __restrict__ Xb) {
    int c = threadIdx.x;
    float mean = ST[c] * (1.f / NN);
    float var = ST[256 + c] * (1.f / NN) - mean * mean;
    float sc = PR[O_BN1W + c] * rsqrtf(var + 1e-5f);
    float sh = PR[O_BN1B + c] - mean * sc;
    for (int n = blockIdx.x; n < NN; n += gridDim.x) {
        float v = fmaf(P[n * 256 + c], sc, sh);
        Xb[n * 256 + c] = (bf16_t)lrelu(v);
    }
}

// ---------------- GEMM: y2 = x1(bf16) @ W2(bf16)^T, f32 out ----------------
__global__ __launch_bounds__(256) void gme_gemm(const bf16_t* __restrict__ Xb,
                                                const bf16_t* __restrict__ W2B,
                                                float* __restrict__ Q) {
    int lane = threadIdx.x & 63;
    int wave = blockIdx.x * 4 + (threadIdx.x >> 6);
    if (wave >= NN / 16) return;
    int m0 = wave * 16;
    int r = lane & 15, q = lane >> 4;
    const bf16_t* arow = Xb + (m0 + r) * 256 + q * 8;
    bf16x8 a[8];
#pragma unroll
    for (int kt = 0; kt < 8; ++kt) a[kt] = *(const bf16x8*)(arow + kt * 32);
#pragma unroll
    for (int nt = 0; nt < 16; ++nt) {
        f32x4 acc = {0.f, 0.f, 0.f, 0.f};
        const bf16_t* brow = W2B + (nt * 16 + r) * 256 + q * 8;
#pragma unroll
        for (int kt = 0; kt < 8; ++kt) {
            bf16x8 bfrag = *(const bf16x8*)(brow + kt * 32);
            acc = __builtin_amdgcn_mfma_f32_16x16x32_bf16(a[kt], bfrag, acc, 0, 0, 0);
        }
        float* yo = Q + (m0 + q * 4) * 256 + nt * 16 + r;
        yo[0] = acc[0]; yo[256] = acc[1]; yo[512] = acc[2]; yo[768] = acc[3];
    }
}

// ---------------- BN2 + LeakyReLU in-place + gate ----------------
__global__ void gme_x2gate(float* __restrict__ P, const float* __restrict__ ST,
                           const float* __restrict__ PR, float* __restrict__ GATE) {
    __shared__ float red[256];
    int c = threadIdx.x;
    float mean = ST[c] * (1.f / NN);
    float var = ST[256 + c] * (1.f / NN) - mean * mean;
    float sc = PR[O_BN2W + c] * rsqrtf(var + 1e-5f);
    float sh = PR[O_BN2B + c] - mean * sc;
    float g = PR[O_GATEW + c];
    float gb0 = PR[O_GATEB];
    for (int n = blockIdx.x; n < NN; n += gridDim.x) {
        float v = lrelu(fmaf(P[n * 256 + c], sc, sh));
        P[n * 256 + c] = v;
        red[c] = v * g;
        __syncthreads();
        for (int s2 = 128; s2 > 0; s2 >>= 1) {
            if (c < s2) red[c] += red[c + s2];
            __syncthreads();
        }
        if (c == 0) GATE[n] = red[0] + gb0;
        __syncthreads();
    }
}

// ---------------- graph segment boundaries (batch is sorted) ----------------
__global__ void gme_gstart(const int* __restrict__ batch, int* __restrict__ GS) {
    int n = blockIdx.x * 256 + threadIdx.x;
    if (n >= NN) return;
    int b = batch[n];
    if (n == 0) {
        for (int g = 0; g <= b; ++g) GS[g] = 0;
    } else {
        int a = batch[n - 1];
        for (int g = a + 1; g <= b; ++g) GS[g] = n;
    }
    if (n == NN - 1) {
        for (int g = b + 1; g <= NG; ++g) GS[g] = NN;
    }
}

// ---------------- attentional aggregation (f32 output!) ----------------
__global__ void gme_attn(const int* __restrict__ GS, const float* __restrict__ GATE,
                         const float* __restrict__ X2, float* __restrict__ out) {
    __shared__ float red[256];
    int g = blockIdx.x, t = threadIdx.x;
    int lo = GS[g], hi = GS[g + 1];
    if (lo >= hi) { out[g * 256 + t] = 0.f; return; }
    // max gate
    float lm = -3.0e38f;
    for (int n = lo + t; n < hi; n += 256) lm = fmaxf(lm, GATE[n]);
    red[t] = lm; __syncthreads();
    for (int s = 128; s > 0; s >>= 1) { if (t < s) red[t] = fmaxf(red[t], red[t + s]); __syncthreads(); }
    float m = red[0]; __syncthreads();
    // sum exp
    float ls = 0.f;
    for (int n = lo + t; n < hi; n += 256) ls += expf(GATE[n] - m);
    red[t] = ls; __syncthreads();
    for (int s = 128; s > 0; s >>= 1) { if (t < s) red[t] += red[t + s]; __syncthreads(); }
    float sinv = 1.f / red[0];
    // weighted sum, thread = channel
    float acc = 0.f;
    for (int n = lo; n < hi; ++n) {
        float w = expf(GATE[n] - m);
        acc = fmaf(w, X2[n * 256 + t], acc);
    }
    out[g * 256 + t] = acc * sinv;
}

extern "C" void kernel_launch(void* const* d_in, const int* in_sizes, int n_in,
                              void* d_out, int out_size, void* d_ws, size_t ws_size,
                              hipStream_t stream) {
    const int* node_ids = (const int*)d_in[0];
    const int* edge_index = (const int*)d_in[1];
    const void* edge_attr_raw = d_in[2];
    const int* batch = (const int*)d_in[3];

    char* ws = (char*)d_ws;
    size_t oP = 0;                        // f32 [50000,256]
    size_t oQ = oP + 51200000;            // f32 [50000,256]
    size_t oXb = oQ + 51200000;           // bf16 [50000,256]
    size_t oSsrc = oXb + 25600000;        // int [800000]
    size_t oSattr = oSsrc + 3200000;      // float4 [800000]
    size_t oRS = oSattr + 12800000;       // int [50001]
    size_t oCUR = oRS + 200064;           // int [50000]
    size_t oTY = oCUR + 200000;           // f32 [51,256]
    size_t oWC1 = oTY + 52224;            // f32 [256,4]
    size_t oCB1 = oWC1 + 4096;            // f32 [256]
    size_t oWC2 = oCB1 + 1024;            // f32 [256,4]
    size_t oCB2 = oWC2 + 4096;            // f32 [256]
    size_t oW2B = oCB2 + 1024;            // bf16 [256,256]
    size_t oST = oW2B + 131072;           // f32 [512]
    size_t oGATE = oST + 2048;            // f32 [50000]
    size_t oGS = oGATE + 200000;          // int [513] -> 2056
    size_t oPR = oGS + 2064;              // f32 [108545]
    size_t oMODE = oPR + 434192;          // int [1]

    float* P = (float*)(ws + oP);
    float* Q = (float*)(ws + oQ);
    bf16_t* Xb = (bf16_t*)(ws + oXb);
    int* Ssrc = (int*)(ws + oSsrc);
    float4* Sattr = (float4*)(ws + oSattr);
    int* RS = (int*)(ws + oRS);
    int* CUR = (int*)(ws + oCUR);
    float* TY = (float*)(ws + oTY);
    float* WC1 = (float*)(ws + oWC1);
    float* CB1 = (float*)(ws + oCB1);
    float* WC2 = (float*)(ws + oWC2);
    float* CB2 = (float*)(ws + oCB2);
    bf16_t* W2B = (bf16_t*)(ws + oW2B);
    float* ST = (float*)(ws + oST);
    float* GATE = (float*)(ws + oGATE);
    int* GS = (int*)(ws + oGS);
    float* PR = (float*)(ws + oPR);
    int* MODE = (int*)(ws + oMODE);

    hipMemsetAsync(CUR, 0, NN * sizeof(int), stream);
    hipMemsetAsync(ST, 0, 512 * sizeof(float), stream);

    gme_mode<<<1, 64, 0, stream>>>((const unsigned*)d_in[9], MODE);
    gme_cvt<<<(NPAR + 255) / 256, 256, 0, stream>>>(
        d_in[4], d_in[5], d_in[6], d_in[7], d_in[8], d_in[9], d_in[10],
        d_in[11], d_in[12], d_in[13], d_in[14], d_in[15], d_in[16],
        d_in[17], d_in[18], MODE, PR);
    gme_setup<<<117, 256, 0, stream>>>(PR, TY, WC1, CB1, WC2, CB2, W2B);
    gme_count<<<NE / 256, 256, 0, stream>>>(edge_index, CUR);
    gme_scan<<<1, 1024, 0, stream>>>(CUR, RS);
    gme_scatter<<<NE / 256, 256, 0, stream>>>(edge_index, edge_attr_raw, MODE,
                                              CUR, Ssrc, Sattr);
    // conv1: y-rows from 51x256 table via node_ids remap
    gme_conv<<<NN / 4, 256, 0, stream>>>(RS, Ssrc, Sattr, TY, node_ids, WC1, CB1, P);
    gme_bnstats<<<256, 256, 0, stream>>>(P, ST);
    gme_x1bf16<<<512, 256, 0, stream>>>(P, ST, PR, Xb);
    hipMemsetAsync(ST, 0, 512 * sizeof(float), stream);
    gme_gemm<<<(NN / 16 + 3) / 4, 256, 0, stream>>>(Xb, W2B, Q);
    // conv2: y-rows direct
    gme_conv<<<NN / 4, 256, 0, stream>>>(RS, Ssrc, Sattr, Q, nullptr, WC2, CB2, P);
    gme_bnstats<<<256, 256, 0, stream>>>(P, ST);
    gme_x2gate<<<1024, 256, 0, stream>>>(P, ST, PR, GATE);
    gme_gstart<<<(NN + 255) / 256, 256, 0, stream>>>(batch, GS);
    gme_attn<<<NG, 256, 0, stream>>>(GS, GATE, P, (float*)d_out);
}

// Round 4
// 665.806 us; speedup vs baseline: 1.2320x; 1.2320x over previous
//
#include <hip/hip_runtime.h>
#include <hip/hip_bf16.h>

#define NN 50000
#define NE 800000
#define NG 512

typedef __bf16 bf16_t;
typedef __bf16 bf16x8 __attribute__((ext_vector_type(8)));
typedef __bf16 bf16x4 __attribute__((ext_vector_type(4)));
typedef float f32x4 __attribute__((ext_vector_type(4)));

__device__ __forceinline__ float lrelu(float v) { return v >= 0.f ? v : 0.01f * v; }

// ---------------- tiny precomputes ----------------
// grid 117 x 256 (inputs are f32 — proven by bit-identical absmax across
// rounds 1/2 where round 2 would have taken the bf16 branch):
//  b<51: TY[b][t]=dot(emb[b],W1[t]);  b==51: WC1/CB1;  b==52: WC2/CB2;  b>=53: W2->bf16
__global__ void gme_setup(const float* __restrict__ emb,
                          const float* __restrict__ c1lw, const float* __restrict__ c1l2w,
                          const float* __restrict__ c1l2b, const float* __restrict__ c1lb,
                          const float* __restrict__ c2lw, const float* __restrict__ c2l2w,
                          const float* __restrict__ c2l2b, const float* __restrict__ c2lb,
                          float* __restrict__ TY, float* __restrict__ WC1, float* __restrict__ CB1,
                          float* __restrict__ WC2, float* __restrict__ CB2,
                          bf16_t* __restrict__ W2B) {
    int b = blockIdx.x, t = threadIdx.x;
    if (b < 51) {
        const float* er = emb + b * 128;
        const float* wr = c1lw + t * 128;
        float s = 0.f;
        for (int k = 0; k < 128; ++k) s += er[k] * wr[k];
        TY[b * 256 + t] = s;
    } else if (b == 51) {
        const float* wr = c1lw + t * 128;
        float a0 = 0, a1 = 0, a2 = 0, a3 = 0, ab = 0;
        for (int k = 0; k < 128; ++k) {
            float w = wr[k];
            a0 += w * c1l2w[k * 4 + 0]; a1 += w * c1l2w[k * 4 + 1];
            a2 += w * c1l2w[k * 4 + 2]; a3 += w * c1l2w[k * 4 + 3];
            ab += w * c1l2b[k];
        }
        WC1[t * 4 + 0] = a0; WC1[t * 4 + 1] = a1; WC1[t * 4 + 2] = a2; WC1[t * 4 + 3] = a3;
        CB1[t] = ab + c1lb[t];
    } else if (b == 52) {
        const float* wr = c2lw + t * 256;
        float a0 = 0, a1 = 0, a2 = 0, a3 = 0, ab = 0;
        for (int k = 0; k < 256; ++k) {
            float w = wr[k];
            a0 += w * c2l2w[k * 4 + 0]; a1 += w * c2l2w[k * 4 + 1];
            a2 += w * c2l2w[k * 4 + 2]; a3 += w * c2l2w[k * 4 + 3];
            ab += w * c2l2b[k];
        }
        WC2[t * 4 + 0] = a0; WC2[t * 4 + 1] = a1; WC2[t * 4 + 2] = a2; WC2[t * 4 + 3] = a3;
        CB2[t] = ab + c2lb[t];
    } else {
        int i0 = (b - 53) * 1024;
        for (int r = 0; r < 4; ++r) {
            int i = i0 + r * 256 + t;
            W2B[i] = (bf16_t)c2lw[i];
        }
    }
}

// ---------------- CSR build ----------------
__global__ void gme_count(const int* __restrict__ ei, int* __restrict__ cnt) {
    int e = blockIdx.x * 256 + threadIdx.x;
    if (e >= NE) return;
    atomicAdd(&cnt[ei[NE + e]], 1);
}

// parallel scan over 50000 counts: 256 blocks x 196 elems
__global__ void gme_scan1(const int* __restrict__ CNT, int* __restrict__ LP,
                          int* __restrict__ BS) {
    __shared__ int lds[256];
    int b = blockIdx.x, t = threadIdx.x;
    int i = b * 196 + t;
    int v = (t < 196 && i < NN) ? CNT[i] : 0;
    lds[t] = v;
    __syncthreads();
    for (int off = 1; off < 256; off <<= 1) {
        int u = (t >= off) ? lds[t - off] : 0;
        __syncthreads();
        lds[t] += u;
        __syncthreads();
    }
    if (t < 196 && i < NN) LP[i] = lds[t] - v;  // exclusive within block
    if (t == 255) BS[b] = lds[255];
}

__global__ void gme_scan2(const int* __restrict__ BS, int* __restrict__ BX,
                          int* __restrict__ RS) {
    __shared__ int lds[256];
    int t = threadIdx.x;
    int v = BS[t];
    lds[t] = v;
    __syncthreads();
    for (int off = 1; off < 256; off <<= 1) {
        int u = (t >= off) ? lds[t - off] : 0;
        __syncthreads();
        lds[t] += u;
        __syncthreads();
    }
    BX[t] = lds[t] - v;
    if (t == 255) RS[NN] = lds[255];
}

__global__ void gme_scan3(const int* __restrict__ LP, const int* __restrict__ BX,
                          int* __restrict__ RS, int* __restrict__ CUR) {
    int b = blockIdx.x, t = threadIdx.x;
    if (t >= 196) return;
    int i = b * 196 + t;
    if (i >= NN) return;
    int v = BX[b] + LP[i];
    RS[i] = v;
    CUR[i] = v;
}

__global__ void gme_scatter(const int* __restrict__ ei, const float4* __restrict__ eattr,
                            int* __restrict__ CUR, int* __restrict__ Ssrc,
                            float4* __restrict__ Sattr) {
    int e = blockIdx.x * 256 + threadIdx.x;
    if (e >= NE) return;
    int d = ei[NE + e];
    int pos = atomicAdd(&CUR[d], 1);
    Ssrc[pos] = ei[e];
    Sattr[pos] = eattr[e];
}

// ---------------- edge aggregation ----------------
// one wave per destination node; lane handles 4 channels. BF=1 -> bf16 y-table.
template <int BF>
__global__ __launch_bounds__(256) void gme_conv(
        const int* __restrict__ RS, const int* __restrict__ Ssrc,
        const float4* __restrict__ Sattr, const float* __restrict__ ybf32,
        const bf16_t* __restrict__ ybf16, const int* __restrict__ remap,
        const float* __restrict__ Wc, const float* __restrict__ cb,
        float* __restrict__ agg) {
    int lane = threadIdx.x & 63;
    int node = blockIdx.x * 4 + (threadIdx.x >> 6);
    if (node >= NN) return;
    const float4* wc4 = (const float4*)Wc;
    int c4 = lane * 4;
    float4 w0 = wc4[c4 + 0], w1 = wc4[c4 + 1], w2 = wc4[c4 + 2], w3 = wc4[c4 + 3];
    float4 bz = ((const float4*)cb)[lane];
    float ax = 0.f, ay = 0.f, az = 0.f, aw = 0.f;
    int rs = RS[node], re = RS[node + 1];
    for (int j = rs; j < re; ++j) {
        int s = Ssrc[j];
        int row = remap ? remap[s] : s;
        float4 a = Sattr[j];
        float4 y;
        if (BF) {
            bf16x4 yb = *((const bf16x4*)(ybf16 + row * 256) + lane);
            y = make_float4((float)yb[0], (float)yb[1], (float)yb[2], (float)yb[3]);
        } else {
            y = *((const float4*)(ybf32 + row * 256) + lane);
        }
        float m0 = fmaf(a.x, w0.x, fmaf(a.y, w0.y, fmaf(a.z, w0.z, fmaf(a.w, w0.w, bz.x)))) + y.x;
        float m1 = fmaf(a.x, w1.x, fmaf(a.y, w1.y, fmaf(a.z, w1.z, fmaf(a.w, w1.w, bz.y)))) + y.y;
        float m2 = fmaf(a.x, w2.x, fmaf(a.y, w2.y, fmaf(a.z, w2.z, fmaf(a.w, w2.w, bz.z)))) + y.z;
        float m3 = fmaf(a.x, w3.x, fmaf(a.y, w3.y, fmaf(a.z, w3.z, fmaf(a.w, w3.w, bz.w)))) + y.w;
        ax += lrelu(m0); ay += lrelu(m1); az += lrelu(m2); aw += lrelu(m3);
    }
    *((float4*)(agg + node * 256) + lane) = make_float4(ax, ay, az, aw);
}

// ---------------- BN stats ----------------
__global__ void gme_bnstats(const float* __restrict__ P, float* __restrict__ ST) {
    int c = threadIdx.x;
    float s = 0.f, q = 0.f;
    for (int n = blockIdx.x; n < NN; n += gridDim.x) {
        float v = P[n * 256 + c];
        s += v; q += v * v;
    }
    atomicAdd(&ST[c], s);
    atomicAdd(&ST[256 + c], q);
}

// ---------------- BN1 + LeakyReLU -> bf16 ----------------
__global__ void gme_x1bf16(const float* __restrict__ P, const float* __restrict__ ST,
                           const float* __restrict__ bw, const float* __restrict__ bb,
                           bf16_t* __restrict__ Xb) {
    int c = threadIdx.x;
    float mean = ST[c] * (1.f / NN);
    float var = ST[256 + c] * (1.f / NN) - mean * mean;
    float sc = bw[c] * rsqrtf(var + 1e-5f);
    float sh = bb[c] - mean * sc;
    for (int n = blockIdx.x; n < NN; n += gridDim.x) {
        float v = fmaf(P[n * 256 + c], sc, sh);
        Xb[n * 256 + c] = (bf16_t)lrelu(v);
    }
}

// ---------------- GEMM: y2 = x1(bf16) @ W2(bf16)^T -> bf16 table ----------------
__global__ __launch_bounds__(256) void gme_gemm(const bf16_t* __restrict__ Xb,
                                                const bf16_t* __restrict__ W2B,
                                                bf16_t* __restrict__ QB) {
    int lane = threadIdx.x & 63;
    int wave = blockIdx.x * 4 + (threadIdx.x >> 6);
    if (wave >= NN / 16) return;
    int m0 = wave * 16;
    int r = lane & 15, q = lane >> 4;
    const bf16_t* arow = Xb + (m0 + r) * 256 + q * 8;
    bf16x8 a[8];
#pragma unroll
    for (int kt = 0; kt < 8; ++kt) a[kt] = *(const bf16x8*)(arow + kt * 32);
#pragma unroll
    for (int nt = 0; nt < 16; ++nt) {
        f32x4 acc = {0.f, 0.f, 0.f, 0.f};
        const bf16_t* brow = W2B + (nt * 16 + r) * 256 + q * 8;
#pragma unroll
        for (int kt = 0; kt < 8; ++kt) {
            bf16x8 bfrag = *(const bf16x8*)(brow + kt * 32);
            acc = __builtin_amdgcn_mfma_f32_16x16x32_bf16(a[kt], bfrag, acc, 0, 0, 0);
        }
        bf16_t* yo = QB + (m0 + q * 4) * 256 + nt * 16 + r;
        yo[0] = (bf16_t)acc[0]; yo[256] = (bf16_t)acc[1];
        yo[512] = (bf16_t)acc[2]; yo[768] = (bf16_t)acc[3];
    }
}

// ---------------- BN2 + LeakyReLU + gate : one wave per node, no barriers ----
__global__ __launch_bounds__(256) void gme_x2g(float* __restrict__ P,
                                               const float* __restrict__ ST,
                                               const float* __restrict__ bw,
                                               const float* __restrict__ bb,
                                               const float* __restrict__ gw,
                                               const float* __restrict__ gb,
                                               float* __restrict__ GATE) {
    int lane = threadIdx.x & 63;
    int node = blockIdx.x * 4 + (threadIdx.x >> 6);
    if (node >= NN) return;
    float4 s = ((const float4*)ST)[lane];
    float4 qq = ((const float4*)(ST + 256))[lane];
    float4 w = ((const float4*)bw)[lane];
    float4 b = ((const float4*)bb)[lane];
    float4 g = ((const float4*)gw)[lane];
    float m0 = s.x * (1.f / NN), m1 = s.y * (1.f / NN), m2 = s.z * (1.f / NN), m3 = s.w * (1.f / NN);
    float sc0 = w.x * rsqrtf(qq.x * (1.f / NN) - m0 * m0 + 1e-5f);
    float sc1 = w.y * rsqrtf(qq.y * (1.f / NN) - m1 * m1 + 1e-5f);
    float sc2 = w.z * rsqrtf(qq.z * (1.f / NN) - m2 * m2 + 1e-5f);
    float sc3 = w.w * rsqrtf(qq.w * (1.f / NN) - m3 * m3 + 1e-5f);
    float sh0 = b.x - m0 * sc0, sh1 = b.y - m1 * sc1, sh2 = b.z - m2 * sc2, sh3 = b.w - m3 * sc3;
    float4* p4 = (float4*)P + node * 64 + lane;
    float4 p = *p4;
    float v0 = lrelu(fmaf(p.x, sc0, sh0));
    float v1 = lrelu(fmaf(p.y, sc1, sh1));
    float v2 = lrelu(fmaf(p.z, sc2, sh2));
    float v3 = lrelu(fmaf(p.w, sc3, sh3));
    *p4 = make_float4(v0, v1, v2, v3);
    float dot = v0 * g.x + v1 * g.y + v2 * g.z + v3 * g.w;
#pragma unroll
    for (int off = 32; off > 0; off >>= 1) dot += __shfl_xor(dot, off, 64);
    if (lane == 0) GATE[node] = dot + gb[0];
}

// ---------------- graph segment boundaries (batch is sorted) ----------------
__global__ void gme_gstart(const int* __restrict__ batch, int* __restrict__ GS) {
    int n = blockIdx.x * 256 + threadIdx.x;
    if (n >= NN) return;
    int b = batch[n];
    if (n == 0) {
        for (int g = 0; g <= b; ++g) GS[g] = 0;
    } else {
        int a = batch[n - 1];
        for (int g = a + 1; g <= b; ++g) GS[g] = n;
    }
    if (n == NN - 1) {
        for (int g = b + 1; g <= NG; ++g) GS[g] = NN;
    }
}

// ---------------- attentional aggregation (f32 output) ----------------
__global__ void gme_attn(const int* __restrict__ GS, const float* __restrict__ GATE,
                         const float* __restrict__ X2, float* __restrict__ out) {
    __shared__ float red[256];
    int g = blockIdx.x, t = threadIdx.x;
    int lo = GS[g], hi = GS[g + 1];
    if (lo >= hi) { out[g * 256 + t] = 0.f; return; }
    float lm = -3.0e38f;
    for (int n = lo + t; n < hi; n += 256) lm = fmaxf(lm, GATE[n]);
    red[t] = lm; __syncthreads();
    for (int s = 128; s > 0; s >>= 1) { if (t < s) red[t] = fmaxf(red[t], red[t + s]); __syncthreads(); }
    float m = red[0]; __syncthreads();
    float ls = 0.f;
    for (int n = lo + t; n < hi; n += 256) ls += expf(GATE[n] - m);
    red[t] = ls; __syncthreads();
    for (int s = 128; s > 0; s >>= 1) { if (t < s) red[t] += red[t + s]; __syncthreads(); }
    float sinv = 1.f / red[0];
    float acc = 0.f;
    for (int n = lo; n < hi; ++n) {
        float w = expf(GATE[n] - m);
        acc = fmaf(w, X2[n * 256 + t], acc);
    }
    out[g * 256 + t] = acc * sinv;
}

extern "C" void kernel_launch(void* const* d_in, const int* in_sizes, int n_in,
                              void* d_out, int out_size, void* d_ws, size_t ws_size,
                              hipStream_t stream) {
    const int* node_ids = (const int*)d_in[0];
    const int* edge_index = (const int*)d_in[1];
    const float4* edge_attr = (const float4*)d_in[2];
    const int* batch = (const int*)d_in[3];
    const float* emb = (const float*)d_in[4];
    const float* c1l2w = (const float*)d_in[5];
    const float* c1l2b = (const float*)d_in[6];
    const float* c1lw = (const float*)d_in[7];
    const float* c1lb = (const float*)d_in[8];
    const float* bn1w = (const float*)d_in[9];
    const float* bn1b = (const float*)d_in[10];
    const float* c2l2w = (const float*)d_in[11];
    const float* c2l2b = (const float*)d_in[12];
    const float* c2lw = (const float*)d_in[13];
    const float* c2lb = (const float*)d_in[14];
    const float* bn2w = (const float*)d_in[15];
    const float* bn2b = (const float*)d_in[16];
    const float* gate_w = (const float*)d_in[17];
    const float* gate_b = (const float*)d_in[18];

    char* ws = (char*)d_ws;
    size_t oP = 0;                        // f32 [50000,256]
    size_t oQB = oP + 51200000;           // bf16 [50000,256]
    size_t oXb = oQB + 25600000;          // bf16 [50000,256]
    size_t oSsrc = oXb + 25600000;        // int [800000]
    size_t oSattr = oSsrc + 3200000;      // float4 [800000]
    size_t oRS = oSattr + 12800000;       // int [50001]
    size_t oCNT = oRS + 200064;           // int [50000]
    size_t oCUR = oCNT + 200000;          // int [50000]
    size_t oLP = oCUR + 200000;           // int [50000]
    size_t oBS = oLP + 200000;            // int [256]
    size_t oBX = oBS + 1024;              // int [256]
    size_t oTY = oBX + 1024;              // f32 [51,256]
    size_t oWC1 = oTY + 52224;            // f32 [256,4]
    size_t oCB1 = oWC1 + 4096;            // f32 [256]
    size_t oWC2 = oCB1 + 1024;            // f32 [256,4]
    size_t oCB2 = oWC2 + 4096;            // f32 [256]
    size_t oW2B = oCB2 + 1024;            // bf16 [256,256]
    size_t oST = oW2B + 131072;           // f32 [1024]: ST1(512)+ST2(512)
    size_t oGATE = oST + 4096;            // f32 [50000]
    size_t oGS = oGATE + 200000;          // int [513]

    float* P = (float*)(ws + oP);
    bf16_t* QB = (bf16_t*)(ws + oQB);
    bf16_t* Xb = (bf16_t*)(ws + oXb);
    int* Ssrc = (int*)(ws + oSsrc);
    float4* Sattr = (float4*)(ws + oSattr);
    int* RS = (int*)(ws + oRS);
    int* CNT = (int*)(ws + oCNT);
    int* CUR = (int*)(ws + oCUR);
    int* LP = (int*)(ws + oLP);
    int* BS = (int*)(ws + oBS);
    int* BX = (int*)(ws + oBX);
    float* TY = (float*)(ws + oTY);
    float* WC1 = (float*)(ws + oWC1);
    float* CB1 = (float*)(ws + oCB1);
    float* WC2 = (float*)(ws + oWC2);
    float* CB2 = (float*)(ws + oCB2);
    bf16_t* W2B = (bf16_t*)(ws + oW2B);
    float* ST1 = (float*)(ws + oST);
    float* ST2 = ST1 + 512;
    float* GATE = (float*)(ws + oGATE);
    int* GS = (int*)(ws + oGS);

    hipMemsetAsync(CNT, 0, NN * sizeof(int), stream);
    hipMemsetAsync(ST1, 0, 1024 * sizeof(float), stream);

    gme_setup<<<117, 256, 0, stream>>>(emb, c1lw, c1l2w, c1l2b, c1lb,
                                       c2lw, c2l2w, c2l2b, c2lb,
                                       TY, WC1, CB1, WC2, CB2, W2B);
    gme_count<<<NE / 256, 256, 0, stream>>>(edge_index, CNT);
    gme_scan1<<<256, 256, 0, stream>>>(CNT, LP, BS);
    gme_scan2<<<1, 256, 0, stream>>>(BS, BX, RS);
    gme_scan3<<<256, 256, 0, stream>>>(LP, BX, RS, CUR);
    gme_scatter<<<NE / 256, 256, 0, stream>>>(edge_index, edge_attr, CUR, Ssrc, Sattr);
    gme_gstart<<<(NN + 255) / 256, 256, 0, stream>>>(batch, GS);
    // conv1: y-rows from 51x256 f32 table via node_ids remap
    gme_conv<0><<<NN / 4, 256, 0, stream>>>(RS, Ssrc, Sattr, TY, nullptr, node_ids,
                                            WC1, CB1, P);
    gme_bnstats<<<256, 256, 0, stream>>>(P, ST1);
    gme_x1bf16<<<512, 256, 0, stream>>>(P, ST1, bn1w, bn1b, Xb);
    gme_gemm<<<(NN / 16 + 3) / 4, 256, 0, stream>>>(Xb, W2B, QB);
    // conv2: y-rows from bf16 table, identity remap
    gme_conv<1><<<NN / 4, 256, 0, stream>>>(RS, Ssrc, Sattr, nullptr, QB, nullptr,
                                            WC2, CB2, P);
    gme_bnstats<<<256, 256, 0, stream>>>(P, ST2);
    gme_x2g<<<NN / 4, 256, 0, stream>>>(P, ST2, bn2w, bn2b, gate_w, gate_b, GATE);
    gme_attn<<<NG, 256, 0, stream>>>(GS, GATE, P, (float*)d_out);
}

// Round 5
// 564.330 us; speedup vs baseline: 1.4535x; 1.1798x over previous
//
#include <hip/hip_runtime.h>
#include <hip/hip_bf16.h>

#define NN 50000
#define NE 800000
#define NG 512

typedef __bf16 bf16_t;
typedef __bf16 bf16x8 __attribute__((ext_vector_type(8)));
typedef __bf16 bf16x4 __attribute__((ext_vector_type(4)));
typedef float f32x4 __attribute__((ext_vector_type(4)));

__device__ __forceinline__ float lrelu(float v) { return v >= 0.f ? v : 0.01f * v; }

// ---------------- tiny precomputes ----------------
__global__ void gme_setup(const float* __restrict__ emb,
                          const float* __restrict__ c1lw, const float* __restrict__ c1l2w,
                          const float* __restrict__ c1l2b, const float* __restrict__ c1lb,
                          const float* __restrict__ c2lw, const float* __restrict__ c2l2w,
                          const float* __restrict__ c2l2b, const float* __restrict__ c2lb,
                          float* __restrict__ TY, float* __restrict__ WC1, float* __restrict__ CB1,
                          float* __restrict__ WC2, float* __restrict__ CB2,
                          bf16_t* __restrict__ W2B) {
    int b = blockIdx.x, t = threadIdx.x;
    if (b < 51) {
        const float* er = emb + b * 128;
        const float* wr = c1lw + t * 128;
        float s = 0.f;
        for (int k = 0; k < 128; ++k) s += er[k] * wr[k];
        TY[b * 256 + t] = s;
    } else if (b == 51) {
        const float* wr = c1lw + t * 128;
        float a0 = 0, a1 = 0, a2 = 0, a3 = 0, ab = 0;
        for (int k = 0; k < 128; ++k) {
            float w = wr[k];
            a0 += w * c1l2w[k * 4 + 0]; a1 += w * c1l2w[k * 4 + 1];
            a2 += w * c1l2w[k * 4 + 2]; a3 += w * c1l2w[k * 4 + 3];
            ab += w * c1l2b[k];
        }
        WC1[t * 4 + 0] = a0; WC1[t * 4 + 1] = a1; WC1[t * 4 + 2] = a2; WC1[t * 4 + 3] = a3;
        CB1[t] = ab + c1lb[t];
    } else if (b == 52) {
        const float* wr = c2lw + t * 256;
        float a0 = 0, a1 = 0, a2 = 0, a3 = 0, ab = 0;
        for (int k = 0; k < 256; ++k) {
            float w = wr[k];
            a0 += w * c2l2w[k * 4 + 0]; a1 += w * c2l2w[k * 4 + 1];
            a2 += w * c2l2w[k * 4 + 2]; a3 += w * c2l2w[k * 4 + 3];
            ab += w * c2l2b[k];
        }
        WC2[t * 4 + 0] = a0; WC2[t * 4 + 1] = a1; WC2[t * 4 + 2] = a2; WC2[t * 4 + 3] = a3;
        CB2[t] = ab + c2lb[t];
    } else {
        int i0 = (b - 53) * 1024;
        for (int r = 0; r < 4; ++r) {
            int i = i0 + r * 256 + t;
            W2B[i] = (bf16_t)c2lw[i];
        }
    }
}

// ---------------- CSR build ----------------
__global__ void gme_count(const int* __restrict__ ei, int* __restrict__ cnt) {
    int e = blockIdx.x * 256 + threadIdx.x;
    if (e >= NE) return;
    atomicAdd(&cnt[ei[NE + e]], 1);
}

__global__ void gme_scan1(const int* __restrict__ CNT, int* __restrict__ LP,
                          int* __restrict__ BS) {
    __shared__ int lds[256];
    int b = blockIdx.x, t = threadIdx.x;
    int i = b * 196 + t;
    int v = (t < 196 && i < NN) ? CNT[i] : 0;
    lds[t] = v;
    __syncthreads();
    for (int off = 1; off < 256; off <<= 1) {
        int u = (t >= off) ? lds[t - off] : 0;
        __syncthreads();
        lds[t] += u;
        __syncthreads();
    }
    if (t < 196 && i < NN) LP[i] = lds[t] - v;
    if (t == 255) BS[b] = lds[255];
}

__global__ void gme_scan2(const int* __restrict__ BS, int* __restrict__ BX,
                          int* __restrict__ RS) {
    __shared__ int lds[256];
    int t = threadIdx.x;
    int v = BS[t];
    lds[t] = v;
    __syncthreads();
    for (int off = 1; off < 256; off <<= 1) {
        int u = (t >= off) ? lds[t - off] : 0;
        __syncthreads();
        lds[t] += u;
        __syncthreads();
    }
    BX[t] = lds[t] - v;
    if (t == 255) RS[NN] = lds[255];
}

__global__ void gme_scan3(const int* __restrict__ LP, const int* __restrict__ BX,
                          int* __restrict__ RS, int* __restrict__ CUR) {
    int b = blockIdx.x, t = threadIdx.x;
    if (t >= 196) return;
    int i = b * 196 + t;
    if (i >= NN) return;
    int v = BX[b] + LP[i];
    RS[i] = v;
    CUR[i] = v;
}

// scatter resolves node_ids too (conv1 loses a dependent gather hop)
__global__ void gme_scatter(const int* __restrict__ ei, const float4* __restrict__ eattr,
                            const int* __restrict__ node_ids,
                            int* __restrict__ CUR, int* __restrict__ S0,
                            int* __restrict__ S1, float4* __restrict__ Sattr) {
    int e = blockIdx.x * 256 + threadIdx.x;
    if (e >= NE) return;
    int s = ei[e];
    int d = ei[NE + e];
    int pos = atomicAdd(&CUR[d], 1);
    S0[pos] = s;
    S1[pos] = node_ids[s];
    Sattr[pos] = eattr[e];
}

// ---------------- edge aggregation ----------------
// one wave per node, lane = 4 channels; 4-edge unroll for memory-level parallelism
template <int BF>
__global__ __launch_bounds__(256) void gme_conv(
        const int* __restrict__ RS, const int* __restrict__ Src,
        const float4* __restrict__ Sattr, const float* __restrict__ ybf32,
        const bf16_t* __restrict__ ybf16,
        const float* __restrict__ Wc, const float* __restrict__ cb,
        float* __restrict__ agg) {
    int lane = threadIdx.x & 63;
    int node = blockIdx.x * 4 + (threadIdx.x >> 6);
    if (node >= NN) return;
    const float4* wc4 = (const float4*)Wc;
    int c4 = lane * 4;
    float4 w0 = wc4[c4 + 0], w1 = wc4[c4 + 1], w2 = wc4[c4 + 2], w3 = wc4[c4 + 3];
    float4 bz = ((const float4*)cb)[lane];
    float ax = 0.f, ay = 0.f, az = 0.f, aw = 0.f;
    int rs = RS[node], re = RS[node + 1];

    auto rowld = [&](int row) -> float4 {
        if (BF) {
            bf16x4 yb = *((const bf16x4*)(ybf16 + row * 256) + lane);
            return make_float4((float)yb[0], (float)yb[1], (float)yb[2], (float)yb[3]);
        }
        return *((const float4*)(ybf32 + row * 256) + lane);
    };
    auto accum = [&](float4 a, float4 y) {
        float m0 = fmaf(a.x, w0.x, fmaf(a.y, w0.y, fmaf(a.z, w0.z, fmaf(a.w, w0.w, bz.x)))) + y.x;
        float m1 = fmaf(a.x, w1.x, fmaf(a.y, w1.y, fmaf(a.z, w1.z, fmaf(a.w, w1.w, bz.y)))) + y.y;
        float m2 = fmaf(a.x, w2.x, fmaf(a.y, w2.y, fmaf(a.z, w2.z, fmaf(a.w, w2.w, bz.z)))) + y.z;
        float m3 = fmaf(a.x, w3.x, fmaf(a.y, w3.y, fmaf(a.z, w3.z, fmaf(a.w, w3.w, bz.w)))) + y.w;
        ax += lrelu(m0); ay += lrelu(m1); az += lrelu(m2); aw += lrelu(m3);
    };

    int j = rs;
    for (; j + 4 <= re; j += 4) {
        int s0 = Src[j], s1 = Src[j + 1], s2 = Src[j + 2], s3 = Src[j + 3];
        float4 a0 = Sattr[j], a1 = Sattr[j + 1], a2 = Sattr[j + 2], a3 = Sattr[j + 3];
        float4 y0 = rowld(s0);
        float4 y1 = rowld(s1);
        float4 y2 = rowld(s2);
        float4 y3 = rowld(s3);
        accum(a0, y0); accum(a1, y1); accum(a2, y2); accum(a3, y3);
    }
    for (; j < re; ++j) {
        int s = Src[j];
        float4 a = Sattr[j];
        accum(a, rowld(s));
    }
    *((float4*)(agg + node * 256) + lane) = make_float4(ax, ay, az, aw);
}

// ---------------- BN stats ----------------
__global__ void gme_bnstats(const float* __restrict__ P, float* __restrict__ ST) {
    int c = threadIdx.x;
    float s = 0.f, q = 0.f;
    for (int n = blockIdx.x; n < NN; n += gridDim.x) {
        float v = P[n * 256 + c];
        s += v; q += v * v;
    }
    atomicAdd(&ST[c], s);
    atomicAdd(&ST[256 + c], q);
}

// ---------------- GEMM with fused BN1+LeakyReLU on the A operand ----------------
// y2 = lrelu(bn1(P)) @ W2^T -> bf16 table
__global__ __launch_bounds__(256) void gme_gemm(const float* __restrict__ P,
                                                const float* __restrict__ ST,
                                                const float* __restrict__ bw,
                                                const float* __restrict__ bb,
                                                const bf16_t* __restrict__ W2B,
                                                bf16_t* __restrict__ QB) {
    __shared__ float s_sc[256], s_sh[256];
    {
        int c = threadIdx.x;
        float mean = ST[c] * (1.f / NN);
        float var = ST[256 + c] * (1.f / NN) - mean * mean;
        float sc = bw[c] * rsqrtf(var + 1e-5f);
        s_sc[c] = sc;
        s_sh[c] = bb[c] - mean * sc;
    }
    __syncthreads();
    int lane = threadIdx.x & 63;
    int wave = blockIdx.x * 4 + (threadIdx.x >> 6);
    if (wave >= NN / 16) return;
    int m0 = wave * 16;
    int r = lane & 15, q = lane >> 4;
    const float* arow = P + (m0 + r) * 256 + q * 8;
    bf16x8 a[8];
#pragma unroll
    for (int kt = 0; kt < 8; ++kt) {
        int k0 = kt * 32 + q * 8;
        float4 u0 = *(const float4*)(arow + kt * 32);
        float4 u1 = *(const float4*)(arow + kt * 32 + 4);
        bf16x8 f;
        f[0] = (bf16_t)lrelu(fmaf(u0.x, s_sc[k0 + 0], s_sh[k0 + 0]));
        f[1] = (bf16_t)lrelu(fmaf(u0.y, s_sc[k0 + 1], s_sh[k0 + 1]));
        f[2] = (bf16_t)lrelu(fmaf(u0.z, s_sc[k0 + 2], s_sh[k0 + 2]));
        f[3] = (bf16_t)lrelu(fmaf(u0.w, s_sc[k0 + 3], s_sh[k0 + 3]));
        f[4] = (bf16_t)lrelu(fmaf(u1.x, s_sc[k0 + 4], s_sh[k0 + 4]));
        f[5] = (bf16_t)lrelu(fmaf(u1.y, s_sc[k0 + 5], s_sh[k0 + 5]));
        f[6] = (bf16_t)lrelu(fmaf(u1.z, s_sc[k0 + 6], s_sh[k0 + 6]));
        f[7] = (bf16_t)lrelu(fmaf(u1.w, s_sc[k0 + 7], s_sh[k0 + 7]));
        a[kt] = f;
    }
#pragma unroll
    for (int nt = 0; nt < 16; ++nt) {
        f32x4 acc = {0.f, 0.f, 0.f, 0.f};
        const bf16_t* brow = W2B + (nt * 16 + r) * 256 + q * 8;
#pragma unroll
        for (int kt = 0; kt < 8; ++kt) {
            bf16x8 bfrag = *(const bf16x8*)(brow + kt * 32);
            acc = __builtin_amdgcn_mfma_f32_16x16x32_bf16(a[kt], bfrag, acc, 0, 0, 0);
        }
        bf16_t* yo = QB + (m0 + q * 4) * 256 + nt * 16 + r;
        yo[0] = (bf16_t)acc[0]; yo[256] = (bf16_t)acc[1];
        yo[512] = (bf16_t)acc[2]; yo[768] = (bf16_t)acc[3];
    }
}

// ---------------- gate only (BN2 applied on the fly, P left raw) ----------------
__global__ __launch_bounds__(256) void gme_x2g(const float* __restrict__ P,
                                               const float* __restrict__ ST,
                                               const float* __restrict__ bw,
                                               const float* __restrict__ bb,
                                               const float* __restrict__ gw,
                                               const float* __restrict__ gb,
                                               float* __restrict__ GATE) {
    int lane = threadIdx.x & 63;
    int node = blockIdx.x * 4 + (threadIdx.x >> 6);
    if (node >= NN) return;
    float4 s = ((const float4*)ST)[lane];
    float4 qq = ((const float4*)(ST + 256))[lane];
    float4 w = ((const float4*)bw)[lane];
    float4 b = ((const float4*)bb)[lane];
    float4 g = ((const float4*)gw)[lane];
    float m0 = s.x * (1.f / NN), m1 = s.y * (1.f / NN), m2 = s.z * (1.f / NN), m3 = s.w * (1.f / NN);
    float sc0 = w.x * rsqrtf(qq.x * (1.f / NN) - m0 * m0 + 1e-5f);
    float sc1 = w.y * rsqrtf(qq.y * (1.f / NN) - m1 * m1 + 1e-5f);
    float sc2 = w.z * rsqrtf(qq.z * (1.f / NN) - m2 * m2 + 1e-5f);
    float sc3 = w.w * rsqrtf(qq.w * (1.f / NN) - m3 * m3 + 1e-5f);
    float sh0 = b.x - m0 * sc0, sh1 = b.y - m1 * sc1, sh2 = b.z - m2 * sc2, sh3 = b.w - m3 * sc3;
    float4 p = ((const float4*)P)[node * 64 + lane];
    float v0 = lrelu(fmaf(p.x, sc0, sh0));
    float v1 = lrelu(fmaf(p.y, sc1, sh1));
    float v2 = lrelu(fmaf(p.z, sc2, sh2));
    float v3 = lrelu(fmaf(p.w, sc3, sh3));
    float dot = v0 * g.x + v1 * g.y + v2 * g.z + v3 * g.w;
#pragma unroll
    for (int off = 32; off > 0; off >>= 1) dot += __shfl_xor(dot, off, 64);
    if (lane == 0) GATE[node] = dot + gb[0];
}

// ---------------- graph segment boundaries (batch is sorted) ----------------
__global__ void gme_gstart(const int* __restrict__ batch, int* __restrict__ GS) {
    int n = blockIdx.x * 256 + threadIdx.x;
    if (n >= NN) return;
    int b = batch[n];
    if (n == 0) {
        for (int g = 0; g <= b; ++g) GS[g] = 0;
    } else {
        int a = batch[n - 1];
        for (int g = a + 1; g <= b; ++g) GS[g] = n;
    }
    if (n == NN - 1) {
        for (int g = b + 1; g <= NG; ++g) GS[g] = NN;
    }
}

// ---------------- attentional aggregation, BN2+lrelu inline (f32 output) ------
__global__ void gme_attn(const int* __restrict__ GS, const float* __restrict__ GATE,
                         const float* __restrict__ P, const float* __restrict__ ST,
                         const float* __restrict__ bw, const float* __restrict__ bb,
                         float* __restrict__ out) {
    __shared__ float red[256];
    int g = blockIdx.x, t = threadIdx.x;
    int lo = GS[g], hi = GS[g + 1];
    if (lo >= hi) { out[g * 256 + t] = 0.f; return; }
    float mean = ST[t] * (1.f / NN);
    float var = ST[256 + t] * (1.f / NN) - mean * mean;
    float sc = bw[t] * rsqrtf(var + 1e-5f);
    float sh = bb[t] - mean * sc;
    float lm = -3.0e38f;
    for (int n = lo + t; n < hi; n += 256) lm = fmaxf(lm, GATE[n]);
    red[t] = lm; __syncthreads();
    for (int s = 128; s > 0; s >>= 1) { if (t < s) red[t] = fmaxf(red[t], red[t + s]); __syncthreads(); }
    float m = red[0]; __syncthreads();
    float ls = 0.f;
    for (int n = lo + t; n < hi; n += 256) ls += expf(GATE[n] - m);
    red[t] = ls; __syncthreads();
    for (int s = 128; s > 0; s >>= 1) { if (t < s) red[t] += red[t + s]; __syncthreads(); }
    float sinv = 1.f / red[0];
    float acc = 0.f;
    int n = lo;
    for (; n + 2 <= hi; n += 2) {
        float w0 = expf(GATE[n] - m), w1 = expf(GATE[n + 1] - m);
        float p0 = P[n * 256 + t], p1 = P[(n + 1) * 256 + t];
        acc = fmaf(w0, lrelu(fmaf(p0, sc, sh)), acc);
        acc = fmaf(w1, lrelu(fmaf(p1, sc, sh)), acc);
    }
    if (n < hi) {
        float w0 = expf(GATE[n] - m);
        acc = fmaf(w0, lrelu(fmaf(P[n * 256 + t], sc, sh)), acc);
    }
    out[g * 256 + t] = acc * sinv;
}

extern "C" void kernel_launch(void* const* d_in, const int* in_sizes, int n_in,
                              void* d_out, int out_size, void* d_ws, size_t ws_size,
                              hipStream_t stream) {
    const int* node_ids = (const int*)d_in[0];
    const int* edge_index = (const int*)d_in[1];
    const float4* edge_attr = (const float4*)d_in[2];
    const int* batch = (const int*)d_in[3];
    const float* emb = (const float*)d_in[4];
    const float* c1l2w = (const float*)d_in[5];
    const float* c1l2b = (const float*)d_in[6];
    const float* c1lw = (const float*)d_in[7];
    const float* c1lb = (const float*)d_in[8];
    const float* bn1w = (const float*)d_in[9];
    const float* bn1b = (const float*)d_in[10];
    const float* c2l2w = (const float*)d_in[11];
    const float* c2l2b = (const float*)d_in[12];
    const float* c2lw = (const float*)d_in[13];
    const float* c2lb = (const float*)d_in[14];
    const float* bn2w = (const float*)d_in[15];
    const float* bn2b = (const float*)d_in[16];
    const float* gate_w = (const float*)d_in[17];
    const float* gate_b = (const float*)d_in[18];

    char* ws = (char*)d_ws;
    size_t oP = 0;                        // f32 [50000,256]
    size_t oQB = oP + 51200000;           // bf16 [50000,256]
    size_t oS0 = oQB + 25600000;          // int [800000] src
    size_t oS1 = oS0 + 3200000;           // int [800000] node_ids[src]
    size_t oSattr = oS1 + 3200000;        // float4 [800000]
    size_t oRS = oSattr + 12800000;       // int [50001]
    size_t oCNT = oRS + 200064;           // int [50000]
    size_t oCUR = oCNT + 200000;          // int [50000]
    size_t oLP = oCUR + 200000;           // int [50000]
    size_t oBS = oLP + 200000;            // int [256]
    size_t oBX = oBS + 1024;              // int [256]
    size_t oTY = oBX + 1024;              // f32 [51,256]
    size_t oWC1 = oTY + 52224;            // f32 [256,4]
    size_t oCB1 = oWC1 + 4096;            // f32 [256]
    size_t oWC2 = oCB1 + 1024;            // f32 [256,4]
    size_t oCB2 = oWC2 + 4096;            // f32 [256]
    size_t oW2B = oCB2 + 1024;            // bf16 [256,256]
    size_t oST = oW2B + 131072;           // f32 [1024]: ST1+ST2
    size_t oGATE = oST + 4096;            // f32 [50000]
    size_t oGS = oGATE + 200000;          // int [513]

    float* P = (float*)(ws + oP);
    bf16_t* QB = (bf16_t*)(ws + oQB);
    int* S0 = (int*)(ws + oS0);
    int* S1 = (int*)(ws + oS1);
    float4* Sattr = (float4*)(ws + oSattr);
    int* RS = (int*)(ws + oRS);
    int* CNT = (int*)(ws + oCNT);
    int* CUR = (int*)(ws + oCUR);
    int* LP = (int*)(ws + oLP);
    int* BS = (int*)(ws + oBS);
    int* BX = (int*)(ws + oBX);
    float* TY = (float*)(ws + oTY);
    float* WC1 = (float*)(ws + oWC1);
    float* CB1 = (float*)(ws + oCB1);
    float* WC2 = (float*)(ws + oWC2);
    float* CB2 = (float*)(ws + oCB2);
    bf16_t* W2B = (bf16_t*)(ws + oW2B);
    float* ST1 = (float*)(ws + oST);
    float* ST2 = ST1 + 512;
    float* GATE = (float*)(ws + oGATE);
    int* GS = (int*)(ws + oGS);

    hipMemsetAsync(CNT, 0, NN * sizeof(int), stream);
    hipMemsetAsync(ST1, 0, 1024 * sizeof(float), stream);

    gme_setup<<<117, 256, 0, stream>>>(emb, c1lw, c1l2w, c1l2b, c1lb,
                                       c2lw, c2l2w, c2l2b, c2lb,
                                       TY, WC1, CB1, WC2, CB2, W2B);
    gme_count<<<NE / 256, 256, 0, stream>>>(edge_index, CNT);
    gme_scan1<<<256, 256, 0, stream>>>(CNT, LP, BS);
    gme_scan2<<<1, 256, 0, stream>>>(BS, BX, RS);
    gme_scan3<<<256, 256, 0, stream>>>(LP, BX, RS, CUR);
    gme_scatter<<<NE / 256, 256, 0, stream>>>(edge_index, edge_attr, node_ids,
                                              CUR, S0, S1, Sattr);
    gme_gstart<<<(NN + 255) / 256, 256, 0, stream>>>(batch, GS);
    // conv1: rows from 51x256 f32 table via pre-mapped S1
    gme_conv<0><<<NN / 4, 256, 0, stream>>>(RS, S1, Sattr, TY, nullptr, WC1, CB1, P);
    gme_bnstats<<<256, 256, 0, stream>>>(P, ST1);
    gme_gemm<<<(NN / 16 + 3) / 4, 256, 0, stream>>>(P, ST1, bn1w, bn1b, W2B, QB);
    // conv2: rows from bf16 y2 table via S0
    gme_conv<1><<<NN / 4, 256, 0, stream>>>(RS, S0, Sattr, nullptr, QB, WC2, CB2, P);
    gme_bnstats<<<256, 256, 0, stream>>>(P, ST2);
    gme_x2g<<<NN / 4, 256, 0, stream>>>(P, ST2, bn2w, bn2b, gate_w, gate_b, GATE);
    gme_attn<<<NG, 256, 0, stream>>>(GS, GATE, P, ST2, bn2w, bn2b, (float*)d_out);
}